// Round 1
// baseline (95.939 us; speedup 1.0000x reference)
//
#include <hip/hip_runtime.h>

// Chamfer distance, B=16, N=M=4096, D=3, fp32.
// v2: rocprof showed the LDS pipe saturated (8192 ds_read_b128/CU over 117K cyc
// = 1 per 14.3 cyc ~= m134's 12-cyc b128 throughput) while real VALU busy was
// ~29% (reported 58% is the gfx94x 4-cyc formula double-counting on SIMD-32).
// Fix: QPL 4 -> 16 so each ds_read_b128 pair feeds 64 VALU inst instead of 16
// -> VALU-bound. 1024 queries/block; targets split in 2 halves across blocks,
// partial per-query mins combined via uint-bit atomicMin (values >= 0 so IEEE
// bits are order-preserving), out pre-filled with +inf by a tiny init kernel.
// grid = (4 qtiles x 2 thalves, 16 batches, 2 dirs) = 256 blocks x 512 thr
// = 1 block/CU (8 waves). Single staging pass, 32 KB LDS reused for the
// cross-wave reduction.

#define CB 16
#define CN 4096
#define CM 4096
#define QPL 16              // queries per lane
#define WVS 8               // waves per block (512 threads)
#define QPB (64 * QPL)      // queries per block = 1024
#define TPB 2048            // targets per block (half the cloud)
#define GPB (TPB / 2)       // pair-groups per block = 1024
#define GRP_PW (GPB / WVS)  // groups per wave = 128

typedef float v4f __attribute__((ext_vector_type(4)));
typedef float v2f __attribute__((ext_vector_type(2)));

// One pair-group (2 targets) vs one query: 3 v_pk_fma_f32 + 1 v_min3_f32.
// Group format: t0 = (x0,x1,y0,y1), t1 = (z0,z1,w0,w1), w = |t|^2.
// d = w - 2(qx*x + qy*y + qz*z); |q|^2 added after the min (constant per row).
__device__ __forceinline__ void grp(const v4f t0, const v4f t1,
                                    const v2f mx, const v2f my, const v2f mz,
                                    float& best)
{
    v2f d;
    asm("v_pk_fma_f32 %0, %1, %2, %3" : "=&v"(d) : "v"(mz), "v"(t1.xy), "v"(t1.zw));
    asm("v_pk_fma_f32 %0, %1, %2, %0" : "+v"(d) : "v"(my), "v"(t0.zw));
    asm("v_pk_fma_f32 %0, %1, %2, %0" : "+v"(d) : "v"(mx), "v"(t0.xy));
    asm("v_min3_f32 %0, %1, %2, %0" : "+v"(best) : "v"(d.x), "v"(d.y));
}

__global__ void init_out(unsigned* __restrict__ out)
{
    out[blockIdx.x * 512 + threadIdx.x] = 0x7F800000u;  // +inf bits
}

__global__ __launch_bounds__(512, 2) void chamfer_min(
    const float* __restrict__ x1, const float* __restrict__ x2,
    unsigned* __restrict__ out)
{
    const int dir   = blockIdx.z;
    const int b     = blockIdx.y;
    const int qtile = blockIdx.x & 3;   // which 1024-query tile
    const int thalf = blockIdx.x >> 2;  // which 2048-target half

    const float* __restrict__ qraw = (dir ? x2 : x1) + (size_t)b * CN * 3;
    const float* __restrict__ traw = (dir ? x1 : x2) + (size_t)b * CM * 3
                                   + (size_t)thalf * TPB * 3;
    unsigned* __restrict__ o = out + (dir ? ((size_t)CB * CN + (size_t)b * CM)
                                          : ((size_t)b * CN)) + qtile * QPB;

    __shared__ v4f tgt_lds[GPB * 2];    // 32 KB; reused as red[] after scan

    const int tid  = threadIdx.x;
    const int lane = tid & 63;
    const int wave = __builtin_amdgcn_readfirstlane(tid >> 6);

    // Load queries (once): lane handles q = qtile*1024 + lane + 64k.
    // Stored only as -2q duplicated pairs; |q|^2 recomputed in the epilogue
    // to keep VGPRs under the spill cliff.
    v2f mx2[QPL], my2[QPL], mz2[QPL];
    #pragma unroll
    for (int k = 0; k < QPL; ++k) {
        const float* qp = qraw + (size_t)3 * (qtile * QPB + lane + 64 * k);
        float qx = qp[0], qy = qp[1], qz = qp[2];
        mx2[k] = (v2f){-2.0f * qx, -2.0f * qx};
        my2[k] = (v2f){-2.0f * qy, -2.0f * qy};
        mz2[k] = (v2f){-2.0f * qz, -2.0f * qz};
    }

    // ---- Stage 2048 targets (single pass): thread t packs targets [4t,4t+4)
    // into pair-groups 2t, 2t+1.
    {
        const v4f* rv = (const v4f*)(traw + (size_t)12 * tid);  // 48B aligned
        v4f r0 = rv[0], r1 = rv[1], r2 = rv[2];
        // r0=(t0x,t0y,t0z,t1x) r1=(t1y,t1z,t2x,t2y) r2=(t2z,t3x,t3y,t3z)
        float w0 = r0.x*r0.x + r0.y*r0.y + r0.z*r0.z;
        float w1 = r0.w*r0.w + r1.x*r1.x + r1.y*r1.y;
        float w2 = r1.z*r1.z + r1.w*r1.w + r2.x*r2.x;
        float w3 = r2.y*r2.y + r2.z*r2.z + r2.w*r2.w;
        tgt_lds[4*tid + 0] = (v4f){r0.x, r0.w, r0.y, r1.x};  // x0,x1,y0,y1
        tgt_lds[4*tid + 1] = (v4f){r0.z, r1.y, w0, w1};      // z0,z1,w0,w1
        tgt_lds[4*tid + 2] = (v4f){r1.z, r2.y, r1.w, r2.z};
        tgt_lds[4*tid + 3] = (v4f){r2.x, r2.w, w2, w3};
    }

    float best[QPL];
    #pragma unroll
    for (int k = 0; k < QPL; ++k) best[k] = 1e30f;

    __syncthreads();

    // ---- Scan: wave w handles local groups [w*128, w*128+128).
    // Per 2-group iteration: 4 ds_read_b128 vs 128 VALU inst -> VALU-bound.
    const v4f* tp = &tgt_lds[wave * GRP_PW * 2];
    #pragma unroll 1
    for (int g = 0; g < GRP_PW; g += 2) {
        v4f a0 = tp[2*g + 0];
        v4f a1 = tp[2*g + 1];
        v4f b0 = tp[2*g + 2];
        v4f b1 = tp[2*g + 3];
        #pragma unroll
        for (int k = 0; k < QPL; ++k)
            grp(a0, a1, mx2[k], my2[k], mz2[k], best[k]);
        #pragma unroll
        for (int k = 0; k < QPL; ++k)
            grp(b0, b1, mx2[k], my2[k], mz2[k], best[k]);
    }
    __syncthreads();

    // ---- Cross-wave min combine (reuse tgt_lds as red[WVS][QPL][64] = 32 KB)
    float* red = (float*)tgt_lds;
    #pragma unroll
    for (int k = 0; k < QPL; ++k)
        red[(wave * QPL + k) * 64 + lane] = best[k];
    __syncthreads();

    // 512 threads finish 1024 outputs: add |q|^2, clamp, atomic-combine the
    // two target-halves via monotone uint bits.
    #pragma unroll
    for (int s = 0; s < 2; ++s) {
        const int idx = tid + s * 512;      // 0..1023 = k*64 + l
        const int k = idx >> 6, l = idx & 63;
        float v = red[k * 64 + l];
        #pragma unroll
        for (int w = 1; w < WVS; ++w)
            v = fminf(v, red[(w * QPL + k) * 64 + l]);
        const float* qp = qraw + (size_t)3 * (qtile * QPB + idx);
        const float nq = qp[0]*qp[0] + qp[1]*qp[1] + qp[2]*qp[2];
        const float val = fmaxf(v + nq, 0.0f);
        atomicMin(&o[idx], __float_as_uint(val));
    }
}

extern "C" void kernel_launch(void* const* d_in, const int* in_sizes, int n_in,
                              void* d_out, int out_size, void* d_ws, size_t ws_size,
                              hipStream_t stream) {
    const float* x1 = (const float*)d_in[0];   // [B,N,3]
    const float* x2 = (const float*)d_in[1];   // [B,M,3]
    unsigned* out = (unsigned*)d_out;

    // Fill out with +inf bits, then min-combine from the main kernel.
    init_out<<<dim3(2 * CB * CN / 512), 512, 0, stream>>>(out);
    chamfer_min<<<dim3(8, CB, 2), 512, 0, stream>>>(x1, x2, out);
}

// Round 2
// 95.321 us; speedup vs baseline: 1.0065x; 1.0065x over previous
//
#include <hip/hip_runtime.h>

// Chamfer distance, B=16, N=M=4096, D=3, fp32.
// v3: R0/R1 cross-fit shows v_pk_fma_f32 is HALF-rate on gfx950 (8 cyc/inst,
// 16 FMA-lanes/cyc/SIMD): R1's 47us matches 96 pk*8 + 32 min3*2 = 832 cyc/iter
// exactly, while the 4-cyc model predicted 24us. Packed fp32 on the DP-width
// path; scalar v_fma_f32 is 2 cyc (m07: 103TF -> 1 FMA/lane/cyc = full 157TF).
// => use scalar FMAs: 6 v_fma + 1 v_min3 per (2 targets x query) = 14 cyc per
// wave-call = 9.1 pairs/cyc/SIMD -> 23.9us VALU floor.
// Also 4-way target split (512 blocks = 2 blocks/CU, 4 waves/SIMD) so LDS
// latency is TLP-hidden. Partial mins combined via monotone uint atomicMin
// (all values >= 0), out pre-filled with +inf bits.

#define CB 16
#define CN 4096
#define CM 4096
#define QPL 16              // queries per lane
#define WVS 8               // waves per block (512 threads)
#define QPB (64 * QPL)      // queries per block = 1024
#define TPB 1024            // targets per block (quarter cloud)
#define GPB (TPB / 2)       // pair-groups per block = 512
#define GRP_PW (GPB / WVS)  // groups per wave = 64

typedef float v4f __attribute__((ext_vector_type(4)));

// One pair-group (2 targets) vs one query: 6 v_fma_f32 + 1 v_min3_f32.
// Group format: t0 = (x0,x1,y0,y1), t1 = (z0,z1,w0,w1), w = |t|^2.
// d_j = w_j - 2(qx*x_j + qy*y_j + qz*z_j); |q|^2 added after the min.
__device__ __forceinline__ void grp(const v4f t0, const v4f t1,
                                    float mx, float my, float mz, float& best)
{
    float d0 = fmaf(mz, t1.x, t1.z);
    float d1 = fmaf(mz, t1.y, t1.w);
    d0 = fmaf(my, t0.x * 0.0f + t0.z, d0);  // placeholder-free below
    d0 = d0; // (structured explicitly to keep chains clear)
    d0 = fmaf(my, t0.z, fmaf(mz, t1.x, t1.z)) == d0 ? d0 : d0; // no-op guard
    // -- real computation (kept linear for the scheduler) --
    float e0 = fmaf(mz, t1.x, t1.z);
    float e1 = fmaf(mz, t1.y, t1.w);
    e0 = fmaf(my, t0.z, e0);
    e1 = fmaf(my, t0.w, e1);
    e0 = fmaf(mx, t0.x, e0);
    e1 = fmaf(mx, t0.y, e1);
    asm("v_min3_f32 %0, %1, %2, %0" : "+v"(best) : "v"(e0), "v"(e1));
}

__global__ void init_out(unsigned* __restrict__ out)
{
    out[blockIdx.x * 512 + threadIdx.x] = 0x7F800000u;  // +inf bits
}

__global__ __launch_bounds__(512, 4) void chamfer_min(
    const float* __restrict__ x1, const float* __restrict__ x2,
    unsigned* __restrict__ out)
{
    const int dir    = blockIdx.z;
    const int b      = blockIdx.y;
    const int qtile  = blockIdx.x & 3;   // which 1024-query tile
    const int tchunk = blockIdx.x >> 2;  // which 1024-target chunk

    const float* __restrict__ qraw = (dir ? x2 : x1) + (size_t)b * CN * 3;
    const float* __restrict__ traw = (dir ? x1 : x2) + (size_t)b * CM * 3
                                   + (size_t)tchunk * TPB * 3;
    unsigned* __restrict__ o = out + (dir ? ((size_t)CB * CN + (size_t)b * CM)
                                          : ((size_t)b * CN)) + qtile * QPB;

    // 32 KB: first 1024 v4f = 512 pair-groups; whole array reused as red[].
    __shared__ v4f smem[2048];

    const int tid  = threadIdx.x;
    const int lane = tid & 63;
    const int wave = __builtin_amdgcn_readfirstlane(tid >> 6);

    // Load queries: lane handles q = qtile*1024 + lane + 64k. Only -2q kept
    // in registers; |q|^2 recomputed in the epilogue (VGPR budget).
    float mx[QPL], my[QPL], mz[QPL];
    #pragma unroll
    for (int k = 0; k < QPL; ++k) {
        const float* qp = qraw + (size_t)3 * (qtile * QPB + lane + 64 * k);
        mx[k] = -2.0f * qp[0];
        my[k] = -2.0f * qp[1];
        mz[k] = -2.0f * qp[2];
    }

    // ---- Stage 1024 targets: threads 0..255 pack targets [4t, 4t+4)
    // into pair-groups 2t, 2t+1 (group: 2 v4f as (x0,x1,y0,y1),(z0,z1,w0,w1)).
    if (tid < 256) {
        const v4f* rv = (const v4f*)(traw + (size_t)12 * tid);  // 48B chunks
        v4f r0 = rv[0], r1 = rv[1], r2 = rv[2];
        // r0=(t0x,t0y,t0z,t1x) r1=(t1y,t1z,t2x,t2y) r2=(t2z,t3x,t3y,t3z)
        float w0 = r0.x*r0.x + r0.y*r0.y + r0.z*r0.z;
        float w1 = r0.w*r0.w + r1.x*r1.x + r1.y*r1.y;
        float w2 = r1.z*r1.z + r1.w*r1.w + r2.x*r2.x;
        float w3 = r2.y*r2.y + r2.z*r2.z + r2.w*r2.w;
        smem[4*tid + 0] = (v4f){r0.x, r0.w, r0.y, r1.x};  // x0,x1,y0,y1
        smem[4*tid + 1] = (v4f){r0.z, r1.y, w0, w1};      // z0,z1,w0,w1
        smem[4*tid + 2] = (v4f){r1.z, r2.y, r1.w, r2.z};
        smem[4*tid + 3] = (v4f){r2.x, r2.w, w2, w3};
    }

    float best[QPL];
    #pragma unroll
    for (int k = 0; k < QPL; ++k) best[k] = 1e30f;

    __syncthreads();

    // ---- Scan: wave w handles local groups [w*64, w*64+64).
    const v4f* tp = &smem[wave * GRP_PW * 2];
    #pragma unroll 1
    for (int g = 0; g < GRP_PW; g += 2) {
        v4f a0 = tp[2*g + 0];
        v4f a1 = tp[2*g + 1];
        v4f b0 = tp[2*g + 2];
        v4f b1 = tp[2*g + 3];
        #pragma unroll
        for (int k = 0; k < QPL; ++k)
            grp(a0, a1, mx[k], my[k], mz[k], best[k]);
        #pragma unroll
        for (int k = 0; k < QPL; ++k)
            grp(b0, b1, mx[k], my[k], mz[k], best[k]);
    }
    __syncthreads();

    // ---- Cross-wave min combine (reuse smem as red[WVS][QPL][64] = 32 KB)
    float* red = (float*)smem;
    #pragma unroll
    for (int k = 0; k < QPL; ++k)
        red[(wave * QPL + k) * 64 + lane] = best[k];
    __syncthreads();

    // 512 threads finish 1024 outputs: add |q|^2, clamp, atomic-combine the
    // four target-chunks via monotone uint bits.
    #pragma unroll
    for (int s = 0; s < 2; ++s) {
        const int idx = tid + s * 512;      // 0..1023 = k*64 + l
        const int k = idx >> 6, l = idx & 63;
        float v = red[k * 64 + l];
        #pragma unroll
        for (int w = 1; w < WVS; ++w)
            v = fminf(v, red[(w * QPL + k) * 64 + l]);
        const float* qp = qraw + (size_t)3 * (qtile * QPB + idx);
        const float nq = qp[0]*qp[0] + qp[1]*qp[1] + qp[2]*qp[2];
        const float val = fmaxf(v + nq, 0.0f);
        atomicMin(&o[idx], __float_as_uint(val));
    }
}

extern "C" void kernel_launch(void* const* d_in, const int* in_sizes, int n_in,
                              void* d_out, int out_size, void* d_ws, size_t ws_size,
                              hipStream_t stream) {
    const float* x1 = (const float*)d_in[0];   // [B,N,3]
    const float* x2 = (const float*)d_in[1];   // [B,M,3]
    unsigned* out = (unsigned*)d_out;

    // Fill out with +inf bits, then min-combine from the main kernel.
    init_out<<<dim3(2 * CB * CN / 512), 512, 0, stream>>>(out);
    chamfer_min<<<dim3(16, CB, 2), 512, 0, stream>>>(x1, x2, out);
}